// Round 6
// baseline (144.631 us; speedup 1.0000x reference)
//
#include <hip/hip_runtime.h>
#include <math.h>

#define BN 8192       // batch size (rows of sim)
#define DF 128        // feature dim
#define NSPLIT 16     // column splits per 64-row strip (one block per (strip,split))
#define CPW 128       // cols per wave = (BN/NSPLIT)/4
#define NT 8          // CPW/16 tiles per wave
#define EPSV 1e-5f
#define THRESH 0.5f

typedef short bf16x8 __attribute__((ext_vector_type(8)));
typedef float f32x4 __attribute__((ext_vector_type(4)));
typedef unsigned short ushortx8 __attribute__((ext_vector_type(8)));

static __device__ __forceinline__ unsigned short f2bf(float f) {
    unsigned u = __float_as_uint(f);
    u += 0x7FFFu + ((u >> 16) & 1u);   // round-to-nearest-even
    return (unsigned short)(u >> 16);
}

// ---------------- kernel 0: f32 -> bf16 convert ----------------
__global__ __launch_bounds__(256) void convert_kernel(const float* __restrict__ in,
                                                      unsigned short* __restrict__ out) {
    int gid = blockIdx.x * 256 + threadIdx.x;       // 8 elems per thread
    const float4* inp = reinterpret_cast<const float4*>(in) + (size_t)gid * 2;
    float4 v0 = inp[0], v1 = inp[1];
    ushortx8 o;
    o[0] = f2bf(v0.x); o[1] = f2bf(v0.y); o[2] = f2bf(v0.z); o[3] = f2bf(v0.w);
    o[4] = f2bf(v1.x); o[5] = f2bf(v1.y); o[6] = f2bf(v1.z); o[7] = f2bf(v1.w);
    *reinterpret_cast<ushortx8*>(out + (size_t)gid * 8) = o;
}

// ---------------- kernel 1: per-row min_pos / max_neg ----------------
// Block = one 64-row strip x one column split (512 cols). Each of 4 waves owns
// ALL 64 rows (hoisted A-frags) and a private 128-col range; partials reduced
// across waves in LDS -> one slot per split.
__global__ __launch_bounds__(256) void phase1_kernel(const unsigned short* __restrict__ fb,
                                                     const int* __restrict__ labels,
                                                     float* __restrict__ minp_out,
                                                     float* __restrict__ maxn_out) {
    __shared__ float lmin[4][64], lmax[4][64];
    const int tid  = threadIdx.x;
    const int wave = tid >> 6, lane = tid & 63;
    const int strip = blockIdx.x >> 4;
    const int split = blockIdx.x & (NSPLIT - 1);
    const int m0 = strip * 64;
    const int l4 = lane & 15, g = lane >> 4;
    const int cbase = split * (BN / NSPLIT) + wave * CPW;
    const bool mayself = (cbase < m0 + 64) && (m0 < cbase + CPW);

    bf16x8 afrag[4][4];
    #pragma unroll
    for (int rt = 0; rt < 4; ++rt)
        #pragma unroll
        for (int kk = 0; kk < 4; ++kk)
            afrag[rt][kk] = *reinterpret_cast<const bf16x8*>(fb + (m0 + rt * 16 + l4) * DF + kk * 32 + g * 8);

    int labr[4][4];
    #pragma unroll
    for (int rt = 0; rt < 4; ++rt)
        #pragma unroll
        for (int r = 0; r < 4; ++r)
            labr[rt][r] = labels[m0 + rt * 16 + g * 4 + r];

    float minp[4][4], maxn[4][4];
    #pragma unroll
    for (int rt = 0; rt < 4; ++rt)
        #pragma unroll
        for (int r = 0; r < 4; ++r) { minp[rt][r] = INFINITY; maxn[rt][r] = -INFINITY; }

    #pragma unroll 2
    for (int t = 0; t < NT; ++t) {
        const int col  = cbase + t * 16 + l4;
        const int labc = labels[col];
        bf16x8 bfrag[4];
        #pragma unroll
        for (int kk = 0; kk < 4; ++kk)
            bfrag[kk] = *reinterpret_cast<const bf16x8*>(fb + col * DF + kk * 32 + g * 8);

        f32x4 acc[4];
        #pragma unroll
        for (int rt = 0; rt < 4; ++rt) acc[rt] = (f32x4){0.f, 0.f, 0.f, 0.f};
        #pragma unroll
        for (int kk = 0; kk < 4; ++kk)
            #pragma unroll
            for (int rt = 0; rt < 4; ++rt)
                acc[rt] = __builtin_amdgcn_mfma_f32_16x16x32_bf16(afrag[rt][kk], bfrag[kk], acc[rt], 0, 0, 0);

        #pragma unroll
        for (int rt = 0; rt < 4; ++rt)
            #pragma unroll
            for (int r = 0; r < 4; ++r) {
                float s = acc[rt][r];
                bool same = (labc == labr[rt][r]);
                bool pok  = (s < 1.0f - EPSV);
                if (mayself) pok = pok && (col != (m0 + rt * 16 + g * 4 + r));
                bool posc = same && pok;
                minp[rt][r] = fminf(minp[rt][r], posc ? s : INFINITY);
                maxn[rt][r] = fmaxf(maxn[rt][r], same ? -INFINITY : s);
            }
    }

    #pragma unroll
    for (int rt = 0; rt < 4; ++rt)
        #pragma unroll
        for (int r = 0; r < 4; ++r) {
            float mp = minp[rt][r], mn = maxn[rt][r];
            #pragma unroll
            for (int m = 1; m < 16; m <<= 1) {
                mp = fminf(mp, __shfl_xor(mp, m, 64));
                mn = fmaxf(mn, __shfl_xor(mn, m, 64));
            }
            if (l4 == 0) {
                int rl = rt * 16 + g * 4 + r;
                lmin[wave][rl] = mp;
                lmax[wave][rl] = mn;
            }
        }
    __syncthreads();
    if (tid < 64) {
        float mp = fminf(fminf(lmin[0][tid], lmin[1][tid]), fminf(lmin[2][tid], lmin[3][tid]));
        float mn = fmaxf(fmaxf(lmax[0][tid], lmax[1][tid]), fmaxf(lmax[2][tid], lmax[3][tid]));
        minp_out[split * BN + m0 + tid] = mp;
        maxn_out[split * BN + m0 + tid] = mn;
    }
}

// ---------------- kernel 1.5: reduce partials -> per-row thresholds ----------------
__global__ __launch_bounds__(256) void thr_reduce_kernel(const float* __restrict__ minp_part,
                                                         const float* __restrict__ maxn_part,
                                                         const float* __restrict__ margin_p,
                                                         float* __restrict__ thrn_out,
                                                         float* __restrict__ tpos_out) {
    int r = blockIdx.x * 256 + threadIdx.x;
    const float margin = *margin_p;
    float mp = INFINITY, mn = -INFINITY;
    #pragma unroll
    for (int s = 0; s < NSPLIT; ++s) {
        mp = fminf(mp, minp_part[s * BN + r]);
        mn = fmaxf(mn, maxn_part[s * BN + r]);
    }
    thrn_out[r] = mp - margin;                      // neg pair needs sim > thrn
    tpos_out[r] = fminf(mn + margin, 1.0f - EPSV);  // pos pair needs sim < tpos
}

// ---------------- kernel 2: masked exp sums ----------------
__global__ __launch_bounds__(256) void phase2_kernel(const unsigned short* __restrict__ fb,
                                                     const int* __restrict__ labels,
                                                     const float* __restrict__ thrn_in,
                                                     const float* __restrict__ tpos_in,
                                                     float* __restrict__ pos_part,
                                                     float* __restrict__ neg_part,
                                                     const float* __restrict__ sp_p,
                                                     const float* __restrict__ sn_p) {
    __shared__ float lpos[4][64], lneg[4][64];
    const int tid  = threadIdx.x;
    const int wave = tid >> 6, lane = tid & 63;
    const int strip = blockIdx.x >> 4;
    const int split = blockIdx.x & (NSPLIT - 1);
    const int m0 = strip * 64;
    const int l4 = lane & 15, g = lane >> 4;
    const int cbase = split * (BN / NSPLIT) + wave * CPW;
    const bool mayself = (cbase < m0 + 64) && (m0 < cbase + CPW);

    const float sp = *sp_p, sn = *sn_p;
    const float L2E = 1.4426950408889634f;
    const float a_pos = -sp * L2E, b_pos =  sp * THRESH * L2E;
    const float a_neg =  sn * L2E, b_neg = -sn * THRESH * L2E;

    bf16x8 afrag[4][4];
    #pragma unroll
    for (int rt = 0; rt < 4; ++rt)
        #pragma unroll
        for (int kk = 0; kk < 4; ++kk)
            afrag[rt][kk] = *reinterpret_cast<const bf16x8*>(fb + (m0 + rt * 16 + l4) * DF + kk * 32 + g * 8);

    int labr[4][4];
    float thrn[4][4], tpos[4][4];
    #pragma unroll
    for (int rt = 0; rt < 4; ++rt)
        #pragma unroll
        for (int r = 0; r < 4; ++r) {
            int rrow = m0 + rt * 16 + g * 4 + r;
            labr[rt][r] = labels[rrow];
            thrn[rt][r] = thrn_in[rrow];
            tpos[rt][r] = tpos_in[rrow];
        }

    float psum[4][4], nsum[4][4];
    #pragma unroll
    for (int rt = 0; rt < 4; ++rt)
        #pragma unroll
        for (int r = 0; r < 4; ++r) { psum[rt][r] = 0.f; nsum[rt][r] = 0.f; }

    #pragma unroll 2
    for (int t = 0; t < NT; ++t) {
        const int col  = cbase + t * 16 + l4;
        const int labc = labels[col];
        bf16x8 bfrag[4];
        #pragma unroll
        for (int kk = 0; kk < 4; ++kk)
            bfrag[kk] = *reinterpret_cast<const bf16x8*>(fb + col * DF + kk * 32 + g * 8);

        f32x4 acc[4];
        #pragma unroll
        for (int rt = 0; rt < 4; ++rt) acc[rt] = (f32x4){0.f, 0.f, 0.f, 0.f};
        #pragma unroll
        for (int kk = 0; kk < 4; ++kk)
            #pragma unroll
            for (int rt = 0; rt < 4; ++rt)
                acc[rt] = __builtin_amdgcn_mfma_f32_16x16x32_bf16(afrag[rt][kk], bfrag[kk], acc[rt], 0, 0, 0);

        #pragma unroll
        for (int rt = 0; rt < 4; ++rt)
            #pragma unroll
            for (int r = 0; r < 4; ++r) {
                float s = acc[rt][r];
                bool same = (labc == labr[rt][r]);
                float thr = same ? tpos[rt][r] : thrn[rt][r];
                float d   = s - thr;
                float aa  = same ? a_pos : a_neg;
                float bb  = same ? b_pos : b_neg;
                float e   = __builtin_amdgcn_exp2f(fmaf(aa, s, bb));
                bool pok  = (d < 0.f);
                if (mayself) pok = pok && (col != (m0 + rt * 16 + g * 4 + r));
                bool posc = same && pok;
                bool negc = (!same) && (d > 0.f);
                psum[rt][r] += posc ? e : 0.f;
                nsum[rt][r] += negc ? e : 0.f;
            }
    }

    #pragma unroll
    for (int rt = 0; rt < 4; ++rt)
        #pragma unroll
        for (int r = 0; r < 4; ++r) {
            float ps = psum[rt][r], ns = nsum[rt][r];
            #pragma unroll
            for (int m = 1; m < 16; m <<= 1) {
                ps += __shfl_xor(ps, m, 64);
                ns += __shfl_xor(ns, m, 64);
            }
            if (l4 == 0) {
                int rl = rt * 16 + g * 4 + r;
                lpos[wave][rl] = ps;
                lneg[wave][rl] = ns;
            }
        }
    __syncthreads();
    if (tid < 64) {
        float ps = lpos[0][tid] + lpos[1][tid] + lpos[2][tid] + lpos[3][tid];
        float ns = lneg[0][tid] + lneg[1][tid] + lneg[2][tid] + lneg[3][tid];
        pos_part[split * BN + m0 + tid] = ps;
        neg_part[split * BN + m0 + tid] = ns;
    }
}

// ---------------- kernel 3a: per-row loss, block partials (32 blocks) ----------------
__global__ __launch_bounds__(256) void row_reduce_kernel(const float* __restrict__ pos_part,
                                                         const float* __restrict__ neg_part,
                                                         const float* __restrict__ sp_p,
                                                         const float* __restrict__ sn_p,
                                                         float* __restrict__ blk_out) {
    const int tid  = threadIdx.x;
    const int wave = tid >> 6, lane = tid & 63;
    const int r = blockIdx.x * 256 + tid;
    const float sp = *sp_p, sn = *sn_p;

    float ps = 0.f, ns = 0.f;
    #pragma unroll
    for (int s = 0; s < NSPLIT; ++s) {           // coalesced: threads contiguous in r
        ps += pos_part[s * BN + r];
        ns += neg_part[s * BN + r];
    }
    bool hasp = ps > 0.f, hasn = ns > 0.f;
    float lsum = (hasp && hasn) ? (log1pf(ps) / sp + log1pf(ns) / sn) : 0.f;
    float ncnt = hasn ? 0.f : 1.f;

    #pragma unroll
    for (int m = 1; m < 64; m <<= 1) {
        lsum += __shfl_xor(lsum, m, 64);
        ncnt += __shfl_xor(ncnt, m, 64);
    }
    __shared__ float sdata[8];
    if (lane == 0) { sdata[wave] = lsum; sdata[4 + wave] = ncnt; }
    __syncthreads();
    if (tid == 0) {
        float t = 0.f, c = 0.f;
        #pragma unroll
        for (int i = 0; i < 4; ++i) { t += sdata[i]; c += sdata[4 + i]; }
        blk_out[blockIdx.x] = t;
        blk_out[32 + blockIdx.x] = c;
    }
}

// ---------------- kernel 3b: final sum over 32 block partials ----------------
__global__ __launch_bounds__(64) void final_sum_kernel(const float* __restrict__ blk_in,
                                                       float* __restrict__ out) {
    const int lane = threadIdx.x;
    float l = (lane < 32) ? blk_in[lane] : 0.f;
    float c = (lane < 32) ? blk_in[32 + lane] : 0.f;
    #pragma unroll
    for (int m = 1; m < 32; m <<= 1) {
        l += __shfl_xor(l, m, 64);
        c += __shfl_xor(c, m, 64);
    }
    if (lane == 0) {
        out[0] = l / (float)BN;
        out[1] = c / (float)BN;
    }
}

extern "C" void kernel_launch(void* const* d_in, const int* in_sizes, int n_in,
                              void* d_out, int out_size, void* d_ws, size_t ws_size,
                              hipStream_t stream) {
    const float* feats    = (const float*)d_in[0];
    const int*   labels   = (const int*)d_in[1];
    const float* margin_p = (const float*)d_in[2];
    const float* sp_p     = (const float*)d_in[3];
    const float* sn_p     = (const float*)d_in[4];
    float* out = (float*)d_out;

    char* ws = (char*)d_ws;
    unsigned short* fb = (unsigned short*)ws;                     // 2 MB bf16 feats
    float* minp_part = (float*)(ws + (size_t)BN * DF * sizeof(unsigned short));
    float* maxn_part = minp_part + NSPLIT * BN;
    float* pos_part  = maxn_part + NSPLIT * BN;
    float* neg_part  = pos_part  + NSPLIT * BN;
    float* thrn      = neg_part  + NSPLIT * BN;
    float* tpos      = thrn + BN;
    float* blk_part  = tpos + BN;                                 // 64 floats

    convert_kernel<<<(BN * DF) / (256 * 8), 256, 0, stream>>>(feats, fb);
    phase1_kernel<<<(BN / 64) * NSPLIT, 256, 0, stream>>>(fb, labels, minp_part, maxn_part);
    thr_reduce_kernel<<<BN / 256, 256, 0, stream>>>(minp_part, maxn_part, margin_p, thrn, tpos);
    phase2_kernel<<<(BN / 64) * NSPLIT, 256, 0, stream>>>(fb, labels, thrn, tpos,
                                                          pos_part, neg_part, sp_p, sn_p);
    row_reduce_kernel<<<32, 256, 0, stream>>>(pos_part, neg_part, sp_p, sn_p, blk_part);
    final_sum_kernel<<<1, 64, 0, stream>>>(blk_part, out);
}

// Round 7
// 112.615 us; speedup vs baseline: 1.2843x; 1.2843x over previous
//
#include <hip/hip_runtime.h>
#include <math.h>

#define BN 8192       // batch size (rows of sim)
#define DF 128        // feature dim
#define NSPLIT 8      // column splits per 64-row strip (one block per (strip,split))
#define CPW 256       // cols per wave = (BN/NSPLIT)/4
#define NT 16         // CPW/16 tiles per wave
#define EPSV 1e-5f
#define THRESH 0.5f

typedef short bf16x8 __attribute__((ext_vector_type(8)));
typedef float f32x4 __attribute__((ext_vector_type(4)));
typedef unsigned short ushortx8 __attribute__((ext_vector_type(8)));

static __device__ __forceinline__ unsigned short f2bf(float f) {
    unsigned u = __float_as_uint(f);
    u += 0x7FFFu + ((u >> 16) & 1u);   // round-to-nearest-even
    return (unsigned short)(u >> 16);
}

// ---------------- kernel 0: f32 -> bf16 convert ----------------
__global__ __launch_bounds__(256) void convert_kernel(const float* __restrict__ in,
                                                      unsigned short* __restrict__ out) {
    int gid = blockIdx.x * 256 + threadIdx.x;       // 8 elems per thread
    const float4* inp = reinterpret_cast<const float4*>(in) + (size_t)gid * 2;
    float4 v0 = inp[0], v1 = inp[1];
    ushortx8 o;
    o[0] = f2bf(v0.x); o[1] = f2bf(v0.y); o[2] = f2bf(v0.z); o[3] = f2bf(v0.w);
    o[4] = f2bf(v1.x); o[5] = f2bf(v1.y); o[6] = f2bf(v1.z); o[7] = f2bf(v1.w);
    *reinterpret_cast<ushortx8*>(out + (size_t)gid * 8) = o;
}

// ---------------- kernel 1: per-row min_pos / max_neg ----------------
// Block = one 64-row strip x one column split (1024 cols). Each of 4 waves owns
// ALL 64 rows (hoisted A-frags) and a private 256-col range. B-tiles are
// software-prefetched 1 tile ahead (register double-buffer) to hide L2 latency
// inside the wave. Partials reduced across waves in LDS -> one slot per split.
__global__ __launch_bounds__(256) void phase1_kernel(const unsigned short* __restrict__ fb,
                                                     const int* __restrict__ labels,
                                                     float* __restrict__ minp_out,
                                                     float* __restrict__ maxn_out) {
    __shared__ float lmin[4][64], lmax[4][64];
    const int tid  = threadIdx.x;
    const int wave = tid >> 6, lane = tid & 63;
    const int strip = blockIdx.x >> 3;
    const int split = blockIdx.x & (NSPLIT - 1);
    const int m0 = strip * 64;
    const int l4 = lane & 15, g = lane >> 4;
    const int cbase = split * (BN / NSPLIT) + wave * CPW;
    const bool mayself = (cbase < m0 + 64) && (m0 < cbase + CPW);

    bf16x8 afrag[4][4];
    #pragma unroll
    for (int rt = 0; rt < 4; ++rt)
        #pragma unroll
        for (int kk = 0; kk < 4; ++kk)
            afrag[rt][kk] = *reinterpret_cast<const bf16x8*>(fb + (m0 + rt * 16 + l4) * DF + kk * 32 + g * 8);

    int labr[4][4];
    #pragma unroll
    for (int rt = 0; rt < 4; ++rt)
        #pragma unroll
        for (int r = 0; r < 4; ++r)
            labr[rt][r] = labels[m0 + rt * 16 + g * 4 + r];

    float minp[4][4], maxn[4][4];
    #pragma unroll
    for (int rt = 0; rt < 4; ++rt)
        #pragma unroll
        for (int r = 0; r < 4; ++r) { minp[rt][r] = INFINITY; maxn[rt][r] = -INFINITY; }

    bf16x8 b0[4], b1[4];
    int lab0, lab1;

    auto loadB = [&](bf16x8 (&bf)[4], int& lab, int t) {
        const int col = cbase + t * 16 + l4;
        lab = labels[col];
        const unsigned short* bp = fb + col * DF + g * 8;
        #pragma unroll
        for (int kk = 0; kk < 4; ++kk)
            bf[kk] = *reinterpret_cast<const bf16x8*>(bp + kk * 32);
    };

    auto computeT = [&](const bf16x8 (&bf)[4], int labc, int t) {
        f32x4 acc[4];
        #pragma unroll
        for (int rt = 0; rt < 4; ++rt) acc[rt] = (f32x4){0.f, 0.f, 0.f, 0.f};
        #pragma unroll
        for (int kk = 0; kk < 4; ++kk)
            #pragma unroll
            for (int rt = 0; rt < 4; ++rt)
                acc[rt] = __builtin_amdgcn_mfma_f32_16x16x32_bf16(afrag[rt][kk], bf[kk], acc[rt], 0, 0, 0);
        const int col = cbase + t * 16 + l4;
        #pragma unroll
        for (int rt = 0; rt < 4; ++rt)
            #pragma unroll
            for (int r = 0; r < 4; ++r) {
                float s = acc[rt][r];
                bool same = (labc == labr[rt][r]);
                bool pok  = (s < 1.0f - EPSV);
                if (mayself) pok = pok && (col != (m0 + rt * 16 + g * 4 + r));
                bool posc = same && pok;
                minp[rt][r] = fminf(minp[rt][r], posc ? s : INFINITY);
                maxn[rt][r] = fmaxf(maxn[rt][r], same ? -INFINITY : s);
            }
    };

    loadB(b0, lab0, 0);
    #pragma unroll 1
    for (int tp = 0; tp < NT / 2; ++tp) {
        const int t0 = tp * 2, t1 = tp * 2 + 1;
        loadB(b1, lab1, t1);             // prefetch while computing t0
        computeT(b0, lab0, t0);
        loadB(b0, lab0, (t1 + 1 < NT) ? t1 + 1 : 0);   // clamp: extra load unused
        computeT(b1, lab1, t1);
    }

    #pragma unroll
    for (int rt = 0; rt < 4; ++rt)
        #pragma unroll
        for (int r = 0; r < 4; ++r) {
            float mp = minp[rt][r], mn = maxn[rt][r];
            #pragma unroll
            for (int m = 1; m < 16; m <<= 1) {
                mp = fminf(mp, __shfl_xor(mp, m, 64));
                mn = fmaxf(mn, __shfl_xor(mn, m, 64));
            }
            if (l4 == 0) {
                int rl = rt * 16 + g * 4 + r;
                lmin[wave][rl] = mp;
                lmax[wave][rl] = mn;
            }
        }
    __syncthreads();
    if (tid < 64) {
        float mp = fminf(fminf(lmin[0][tid], lmin[1][tid]), fminf(lmin[2][tid], lmin[3][tid]));
        float mn = fmaxf(fmaxf(lmax[0][tid], lmax[1][tid]), fmaxf(lmax[2][tid], lmax[3][tid]));
        minp_out[split * BN + m0 + tid] = mp;
        maxn_out[split * BN + m0 + tid] = mn;
    }
}

// ---------------- kernel 1.5: reduce partials -> per-row thresholds ----------------
__global__ __launch_bounds__(256) void thr_reduce_kernel(const float* __restrict__ minp_part,
                                                         const float* __restrict__ maxn_part,
                                                         const float* __restrict__ margin_p,
                                                         float* __restrict__ thrn_out,
                                                         float* __restrict__ tpos_out) {
    int r = blockIdx.x * 256 + threadIdx.x;
    const float margin = *margin_p;
    float mp = INFINITY, mn = -INFINITY;
    #pragma unroll
    for (int s = 0; s < NSPLIT; ++s) {
        mp = fminf(mp, minp_part[s * BN + r]);
        mn = fmaxf(mn, maxn_part[s * BN + r]);
    }
    thrn_out[r] = mp - margin;                      // neg pair needs sim > thrn
    tpos_out[r] = fminf(mn + margin, 1.0f - EPSV);  // pos pair needs sim < tpos
}

// ---------------- kernel 2: masked exp sums ----------------
__global__ __launch_bounds__(256) void phase2_kernel(const unsigned short* __restrict__ fb,
                                                     const int* __restrict__ labels,
                                                     const float* __restrict__ thrn_in,
                                                     const float* __restrict__ tpos_in,
                                                     float* __restrict__ pos_part,
                                                     float* __restrict__ neg_part,
                                                     const float* __restrict__ sp_p,
                                                     const float* __restrict__ sn_p) {
    __shared__ float lpos[4][64], lneg[4][64];
    const int tid  = threadIdx.x;
    const int wave = tid >> 6, lane = tid & 63;
    const int strip = blockIdx.x >> 3;
    const int split = blockIdx.x & (NSPLIT - 1);
    const int m0 = strip * 64;
    const int l4 = lane & 15, g = lane >> 4;
    const int cbase = split * (BN / NSPLIT) + wave * CPW;
    const bool mayself = (cbase < m0 + 64) && (m0 < cbase + CPW);

    const float sp = *sp_p, sn = *sn_p;
    const float L2E = 1.4426950408889634f;
    const float a_pos = -sp * L2E, b_pos =  sp * THRESH * L2E;
    const float a_neg =  sn * L2E, b_neg = -sn * THRESH * L2E;

    bf16x8 afrag[4][4];
    #pragma unroll
    for (int rt = 0; rt < 4; ++rt)
        #pragma unroll
        for (int kk = 0; kk < 4; ++kk)
            afrag[rt][kk] = *reinterpret_cast<const bf16x8*>(fb + (m0 + rt * 16 + l4) * DF + kk * 32 + g * 8);

    int labr[4][4];
    float thrn[4][4], tpos[4][4];
    #pragma unroll
    for (int rt = 0; rt < 4; ++rt)
        #pragma unroll
        for (int r = 0; r < 4; ++r) {
            int rrow = m0 + rt * 16 + g * 4 + r;
            labr[rt][r] = labels[rrow];
            thrn[rt][r] = thrn_in[rrow];
            tpos[rt][r] = tpos_in[rrow];
        }

    float psum[4][4], nsum[4][4];
    #pragma unroll
    for (int rt = 0; rt < 4; ++rt)
        #pragma unroll
        for (int r = 0; r < 4; ++r) { psum[rt][r] = 0.f; nsum[rt][r] = 0.f; }

    bf16x8 b0[4], b1[4];
    int lab0, lab1;

    auto loadB = [&](bf16x8 (&bf)[4], int& lab, int t) {
        const int col = cbase + t * 16 + l4;
        lab = labels[col];
        const unsigned short* bp = fb + col * DF + g * 8;
        #pragma unroll
        for (int kk = 0; kk < 4; ++kk)
            bf[kk] = *reinterpret_cast<const bf16x8*>(bp + kk * 32);
    };

    auto computeT = [&](const bf16x8 (&bf)[4], int labc, int t) {
        f32x4 acc[4];
        #pragma unroll
        for (int rt = 0; rt < 4; ++rt) acc[rt] = (f32x4){0.f, 0.f, 0.f, 0.f};
        #pragma unroll
        for (int kk = 0; kk < 4; ++kk)
            #pragma unroll
            for (int rt = 0; rt < 4; ++rt)
                acc[rt] = __builtin_amdgcn_mfma_f32_16x16x32_bf16(afrag[rt][kk], bf[kk], acc[rt], 0, 0, 0);
        const int col = cbase + t * 16 + l4;
        #pragma unroll
        for (int rt = 0; rt < 4; ++rt)
            #pragma unroll
            for (int r = 0; r < 4; ++r) {
                float s = acc[rt][r];
                bool same = (labc == labr[rt][r]);
                float thr = same ? tpos[rt][r] : thrn[rt][r];
                float d   = s - thr;
                float aa  = same ? a_pos : a_neg;
                float bb  = same ? b_pos : b_neg;
                float e   = __builtin_amdgcn_exp2f(fmaf(aa, s, bb));
                bool pok  = (d < 0.f);
                if (mayself) pok = pok && (col != (m0 + rt * 16 + g * 4 + r));
                bool posc = same && pok;
                bool negc = (!same) && (d > 0.f);
                psum[rt][r] += posc ? e : 0.f;
                nsum[rt][r] += negc ? e : 0.f;
            }
    };

    loadB(b0, lab0, 0);
    #pragma unroll 1
    for (int tp = 0; tp < NT / 2; ++tp) {
        const int t0 = tp * 2, t1 = tp * 2 + 1;
        loadB(b1, lab1, t1);
        computeT(b0, lab0, t0);
        loadB(b0, lab0, (t1 + 1 < NT) ? t1 + 1 : 0);
        computeT(b1, lab1, t1);
    }

    #pragma unroll
    for (int rt = 0; rt < 4; ++rt)
        #pragma unroll
        for (int r = 0; r < 4; ++r) {
            float ps = psum[rt][r], ns = nsum[rt][r];
            #pragma unroll
            for (int m = 1; m < 16; m <<= 1) {
                ps += __shfl_xor(ps, m, 64);
                ns += __shfl_xor(ns, m, 64);
            }
            if (l4 == 0) {
                int rl = rt * 16 + g * 4 + r;
                lpos[wave][rl] = ps;
                lneg[wave][rl] = ns;
            }
        }
    __syncthreads();
    if (tid < 64) {
        float ps = lpos[0][tid] + lpos[1][tid] + lpos[2][tid] + lpos[3][tid];
        float ns = lneg[0][tid] + lneg[1][tid] + lneg[2][tid] + lneg[3][tid];
        pos_part[split * BN + m0 + tid] = ps;
        neg_part[split * BN + m0 + tid] = ns;
    }
}

// ---------------- kernel 3a: per-row loss, block partials (32 blocks) ----------------
__global__ __launch_bounds__(256) void row_reduce_kernel(const float* __restrict__ pos_part,
                                                         const float* __restrict__ neg_part,
                                                         const float* __restrict__ sp_p,
                                                         const float* __restrict__ sn_p,
                                                         float* __restrict__ blk_out) {
    const int tid  = threadIdx.x;
    const int wave = tid >> 6, lane = tid & 63;
    const int r = blockIdx.x * 256 + tid;
    const float sp = *sp_p, sn = *sn_p;

    float ps = 0.f, ns = 0.f;
    #pragma unroll
    for (int s = 0; s < NSPLIT; ++s) {           // coalesced: threads contiguous in r
        ps += pos_part[s * BN + r];
        ns += neg_part[s * BN + r];
    }
    bool hasp = ps > 0.f, hasn = ns > 0.f;
    float lsum = (hasp && hasn) ? (log1pf(ps) / sp + log1pf(ns) / sn) : 0.f;
    float ncnt = hasn ? 0.f : 1.f;

    #pragma unroll
    for (int m = 1; m < 64; m <<= 1) {
        lsum += __shfl_xor(lsum, m, 64);
        ncnt += __shfl_xor(ncnt, m, 64);
    }
    __shared__ float sdata[8];
    if (lane == 0) { sdata[wave] = lsum; sdata[4 + wave] = ncnt; }
    __syncthreads();
    if (tid == 0) {
        float t = 0.f, c = 0.f;
        #pragma unroll
        for (int i = 0; i < 4; ++i) { t += sdata[i]; c += sdata[4 + i]; }
        blk_out[blockIdx.x] = t;
        blk_out[32 + blockIdx.x] = c;
    }
}

// ---------------- kernel 3b: final sum over 32 block partials ----------------
__global__ __launch_bounds__(64) void final_sum_kernel(const float* __restrict__ blk_in,
                                                       float* __restrict__ out) {
    const int lane = threadIdx.x;
    float l = (lane < 32) ? blk_in[lane] : 0.f;
    float c = (lane < 32) ? blk_in[32 + lane] : 0.f;
    #pragma unroll
    for (int m = 1; m < 32; m <<= 1) {
        l += __shfl_xor(l, m, 64);
        c += __shfl_xor(c, m, 64);
    }
    if (lane == 0) {
        out[0] = l / (float)BN;
        out[1] = c / (float)BN;
    }
}

extern "C" void kernel_launch(void* const* d_in, const int* in_sizes, int n_in,
                              void* d_out, int out_size, void* d_ws, size_t ws_size,
                              hipStream_t stream) {
    const float* feats    = (const float*)d_in[0];
    const int*   labels   = (const int*)d_in[1];
    const float* margin_p = (const float*)d_in[2];
    const float* sp_p     = (const float*)d_in[3];
    const float* sn_p     = (const float*)d_in[4];
    float* out = (float*)d_out;

    char* ws = (char*)d_ws;
    unsigned short* fb = (unsigned short*)ws;                     // 2 MB bf16 feats
    float* minp_part = (float*)(ws + (size_t)BN * DF * sizeof(unsigned short));
    float* maxn_part = minp_part + NSPLIT * BN;
    float* pos_part  = maxn_part + NSPLIT * BN;
    float* neg_part  = pos_part  + NSPLIT * BN;
    float* thrn      = neg_part  + NSPLIT * BN;
    float* tpos      = thrn + BN;
    float* blk_part  = tpos + BN;                                 // 64 floats

    convert_kernel<<<(BN * DF) / (256 * 8), 256, 0, stream>>>(feats, fb);
    phase1_kernel<<<(BN / 64) * NSPLIT, 256, 0, stream>>>(fb, labels, minp_part, maxn_part);
    thr_reduce_kernel<<<BN / 256, 256, 0, stream>>>(minp_part, maxn_part, margin_p, thrn, tpos);
    phase2_kernel<<<(BN / 64) * NSPLIT, 256, 0, stream>>>(fb, labels, thrn, tpos,
                                                          pos_part, neg_part, sp_p, sn_p);
    row_reduce_kernel<<<32, 256, 0, stream>>>(pos_part, neg_part, sp_p, sn_p, blk_part);
    final_sum_kernel<<<1, 64, 0, stream>>>(blk_part, out);
}